// Round 1
// baseline (663.522 us; speedup 1.0000x reference)
//
#include <hip/hip_runtime.h>

// GaussianActionDistGenerator: dual projection (mean/std) + masked tanh-clipped scores.
// B=8, L=2048, D=128. out = (s_mean [B,L,L], s_std [B,L,L]) f32, concatenated.

#define B_ 8
#define L_ 2048
#define D_ 128
#define NP (B_ * L_ * D_)            // 2,097,152 elems per projection array
#define BLL ((size_t)B_ * L_ * L_)   // 33,554,432 elems per output tensor

typedef __attribute__((ext_vector_type(8))) short short8;
typedef __attribute__((ext_vector_type(4))) float f32x4;

__device__ __forceinline__ unsigned short f32_bf16(float x) {
  unsigned u = __float_as_uint(x);
  u += 0x7FFF + ((u >> 16) & 1);   // round-to-nearest-even on the bf16 boundary
  return (unsigned short)(u >> 16);
}
__device__ __forceinline__ float bf16_f32(unsigned short h) {
  return __uint_as_float(((unsigned)h) << 16);
}
__device__ __forceinline__ float fast_tanh(float x) {
  // tanh(x) = 1 - 2/(exp(2x)+1); saturates correctly at +/-inf
  float e = __expf(2.0f * x);
  return 1.0f - 2.0f * __builtin_amdgcn_rcpf(e + 1.0f);
}

// ---------------------------------------------------------------------------
// Kernel 0: transpose weights [k][n] -> [n][k] and split f32 -> bf16 hi/lo.
// WT layout (ushort): WT[p*16384 + n*128 + k] (hi), WT[(4+p)*16384 + ...] (lo)
// ---------------------------------------------------------------------------
__global__ __launch_bounds__(256) void prep_w(
    const float* __restrict__ w0, const float* __restrict__ w1,
    const float* __restrict__ w2, const float* __restrict__ w3,
    unsigned short* __restrict__ WT) {
  int p = blockIdx.x;
  const float* W = (p == 0) ? w0 : (p == 1) ? w1 : (p == 2) ? w2 : w3;
  int idx = blockIdx.y * 256 + threadIdx.x;   // 0..16383 = k*128+n
  int k = idx >> 7, n = idx & 127;
  float v = W[idx];
  unsigned short h = f32_bf16(v);
  WT[p * 16384 + n * 128 + k] = h;
  WT[(4 + p) * 16384 + n * 128 + k] = f32_bf16(v - bf16_f32(h));
}

// ---------------------------------------------------------------------------
// Kernel 1: projections. y=0: query -> qm (p0), qs (p2); y=1: key -> km (p1), ks (p3).
// Each block: 64 tokens, 4 waves x 16 tokens. MFMA 16x16x32 bf16, hi/lo 3-product split.
// Output P (ushort): P[p*NP + token*128 + d] hi, P[(4+p)*NP + ...] lo.
// ---------------------------------------------------------------------------
__global__ __launch_bounds__(256) void proj_k(
    const float* __restrict__ query, const float* __restrict__ key,
    const float* __restrict__ bqm, const float* __restrict__ bkm,
    const float* __restrict__ bqs, const float* __restrict__ bks,
    const unsigned short* __restrict__ WT,
    unsigned short* __restrict__ P) {
  const int y = blockIdx.y;
  const float* x = y ? key : query;
  const float* bias_m = y ? bkm : bqm;
  const float* bias_s = y ? bks : bqs;
  const int pm = y, ps = y + 2;
  const int wave = threadIdx.x >> 6, lane = threadIdx.x & 63;
  const int lr = lane & 15, kq = lane >> 4;
  const int rowbase = blockIdx.x * 64 + wave * 16;

  const unsigned short* wmh = WT + pm * 16384;
  const unsigned short* wml = WT + (4 + pm) * 16384;
  const unsigned short* wsh = WT + ps * 16384;
  const unsigned short* wsl = WT + (4 + ps) * 16384;

  f32x4 accm[8], accs[8];
#pragma unroll
  for (int i = 0; i < 8; i++) {
    accm[i] = f32x4{0.f, 0.f, 0.f, 0.f};
    accs[i] = f32x4{0.f, 0.f, 0.f, 0.f};
  }

#pragma unroll
  for (int ks = 0; ks < 4; ks++) {
    const int koff = ks * 32 + kq * 8;
    const float* xp = x + (size_t)(rowbase + lr) * D_ + koff;
    short8 a_hi, a_lo;
#pragma unroll
    for (int j = 0; j < 8; j++) {
      float v = xp[j];
      unsigned short h = f32_bf16(v);
      a_hi[j] = (short)h;
      a_lo[j] = (short)f32_bf16(v - bf16_f32(h));
    }
#pragma unroll
    for (int nt = 0; nt < 8; nt++) {
      const int wo = (nt * 16 + lr) * 128 + koff;
      short8 bh = *(const short8*)(wmh + wo);
      short8 bl = *(const short8*)(wml + wo);
      accm[nt] = __builtin_amdgcn_mfma_f32_16x16x32_bf16(a_hi, bh, accm[nt], 0, 0, 0);
      accm[nt] = __builtin_amdgcn_mfma_f32_16x16x32_bf16(a_lo, bh, accm[nt], 0, 0, 0);
      accm[nt] = __builtin_amdgcn_mfma_f32_16x16x32_bf16(a_hi, bl, accm[nt], 0, 0, 0);
      short8 ch = *(const short8*)(wsh + wo);
      short8 cl = *(const short8*)(wsl + wo);
      accs[nt] = __builtin_amdgcn_mfma_f32_16x16x32_bf16(a_hi, ch, accs[nt], 0, 0, 0);
      accs[nt] = __builtin_amdgcn_mfma_f32_16x16x32_bf16(a_lo, ch, accs[nt], 0, 0, 0);
      accs[nt] = __builtin_amdgcn_mfma_f32_16x16x32_bf16(a_hi, cl, accs[nt], 0, 0, 0);
    }
  }

  unsigned short* Pmh = P + pm * NP;
  unsigned short* Pml = P + (4 + pm) * NP;
  unsigned short* Psh = P + ps * NP;
  unsigned short* Psl = P + (4 + ps) * NP;
#pragma unroll
  for (int nt = 0; nt < 8; nt++) {
    const int col = nt * 16 + lr;
    const float bm = bias_m[col];
    const float bs = bias_s[col];
#pragma unroll
    for (int r = 0; r < 4; r++) {
      const int token = rowbase + kq * 4 + r;
      const int o = token * D_ + col;
      float vm = accm[nt][r] + bm;
      unsigned short h = f32_bf16(vm);
      Pmh[o] = h;
      Pml[o] = f32_bf16(vm - bf16_f32(h));
      float vs = accs[nt][r] + bs;
      unsigned short g = f32_bf16(vs);
      Psh[o] = g;
      Psl[o] = f32_bf16(vs - bf16_f32(g));
    }
  }
}

// ---------------------------------------------------------------------------
// Kernel 2: masked scores. Per block: one batch, 128x128 output tile,
// 4 waves in 2x2, each wave 64x64. NT GEMM over D=128, hi/lo 3-product split,
// mean and std fused (one mask read). Epilogue: tanh transform + masked write.
// ---------------------------------------------------------------------------
__global__ __launch_bounds__(256, 2) void scores_k(
    const unsigned short* __restrict__ P,
    const int* __restrict__ mask,
    float* __restrict__ out) {
  const int b = blockIdx.z;
  const int q0 = blockIdx.y * 128, c0 = blockIdx.x * 128;
  const int wave = threadIdx.x >> 6, lane = threadIdx.x & 63;
  const int wr = wave >> 1, wc = wave & 1;
  const int lr = lane & 15, kq = lane >> 4;

  const int qrow = b * L_ + q0 + wr * 64;
  const int crow = b * L_ + c0 + wc * 64;
  const unsigned short* Qmh = P + 0 * NP + (size_t)qrow * D_;
  const unsigned short* Qml = P + 4 * NP + (size_t)qrow * D_;
  const unsigned short* Kmh = P + 1 * NP + (size_t)crow * D_;
  const unsigned short* Kml = P + 5 * NP + (size_t)crow * D_;
  const unsigned short* Qsh = P + 2 * NP + (size_t)qrow * D_;
  const unsigned short* Qsl = P + 6 * NP + (size_t)qrow * D_;
  const unsigned short* Ksh = P + 3 * NP + (size_t)crow * D_;
  const unsigned short* Ksl = P + 7 * NP + (size_t)crow * D_;

  f32x4 am[4][4], as_[4][4];
#pragma unroll
  for (int i = 0; i < 4; i++)
#pragma unroll
    for (int j = 0; j < 4; j++) {
      am[i][j] = f32x4{0.f, 0.f, 0.f, 0.f};
      as_[i][j] = f32x4{0.f, 0.f, 0.f, 0.f};
    }

#pragma unroll
  for (int ks = 0; ks < 4; ks++) {
    const int koff = ks * 32 + kq * 8;
    short8 qh[4], ql[4], kh[4], kl[4];
#pragma unroll
    for (int t = 0; t < 4; t++) {
      const int ro = (t * 16 + lr) * D_ + koff;
      qh[t] = *(const short8*)(Qmh + ro);
      ql[t] = *(const short8*)(Qml + ro);
      kh[t] = *(const short8*)(Kmh + ro);
      kl[t] = *(const short8*)(Kml + ro);
    }
#pragma unroll
    for (int mi = 0; mi < 4; mi++)
#pragma unroll
      for (int ni = 0; ni < 4; ni++) {
        am[mi][ni] = __builtin_amdgcn_mfma_f32_16x16x32_bf16(qh[mi], kh[ni], am[mi][ni], 0, 0, 0);
        am[mi][ni] = __builtin_amdgcn_mfma_f32_16x16x32_bf16(ql[mi], kh[ni], am[mi][ni], 0, 0, 0);
        am[mi][ni] = __builtin_amdgcn_mfma_f32_16x16x32_bf16(qh[mi], kl[ni], am[mi][ni], 0, 0, 0);
      }
#pragma unroll
    for (int t = 0; t < 4; t++) {
      const int ro = (t * 16 + lr) * D_ + koff;
      qh[t] = *(const short8*)(Qsh + ro);
      ql[t] = *(const short8*)(Qsl + ro);
      kh[t] = *(const short8*)(Ksh + ro);
      kl[t] = *(const short8*)(Ksl + ro);
    }
#pragma unroll
    for (int mi = 0; mi < 4; mi++)
#pragma unroll
      for (int ni = 0; ni < 4; ni++) {
        as_[mi][ni] = __builtin_amdgcn_mfma_f32_16x16x32_bf16(qh[mi], kh[ni], as_[mi][ni], 0, 0, 0);
        as_[mi][ni] = __builtin_amdgcn_mfma_f32_16x16x32_bf16(ql[mi], kh[ni], as_[mi][ni], 0, 0, 0);
        as_[mi][ni] = __builtin_amdgcn_mfma_f32_16x16x32_bf16(qh[mi], kl[ni], as_[mi][ni], 0, 0, 0);
      }
  }

  const float rs = 0.08838834764831845f;  // 1/sqrt(128)
#pragma unroll
  for (int mi = 0; mi < 4; mi++) {
#pragma unroll
    for (int r = 0; r < 4; r++) {
      const int q = q0 + wr * 64 + mi * 16 + kq * 4 + r;
      const size_t ob = ((size_t)b * L_ + q) * L_;
      const int kb = c0 + wc * 64;
#pragma unroll
      for (int ni = 0; ni < 4; ni++) {
        const int k = kb + ni * 16 + lr;
        const int mv = mask[ob + k];
        float tm = fast_tanh(am[mi][ni][r] * rs);
        out[ob + k] = mv ? (0.5f * tm + 0.5f) : 0.0f;
        float ts = fast_tanh(as_[mi][ni][r] * rs);
        out[BLL + ob + k] = mv ? (4.0f * ts - 6.0f) : -10.0f;
      }
    }
  }
}

extern "C" void kernel_launch(void* const* d_in, const int* in_sizes, int n_in,
                              void* d_out, int out_size, void* d_ws, size_t ws_size,
                              hipStream_t stream) {
  const float* query = (const float*)d_in[0];
  const float* key   = (const float*)d_in[1];
  const int*   mask  = (const int*)d_in[2];
  const float* Wqm   = (const float*)d_in[3];
  const float* bqm   = (const float*)d_in[4];
  const float* Wkm   = (const float*)d_in[5];
  const float* bkm   = (const float*)d_in[6];
  const float* Wqs   = (const float*)d_in[7];
  const float* bqs   = (const float*)d_in[8];
  const float* Wks   = (const float*)d_in[9];
  const float* bks   = (const float*)d_in[10];

  unsigned short* P  = (unsigned short*)d_ws;       // 8 * NP ushorts = 33.55 MB
  unsigned short* WT = P + 8 * NP;                  // 8 * 16384 ushorts

  prep_w<<<dim3(4, 64), 256, 0, stream>>>(Wqm, Wkm, Wqs, Wks, WT);
  proj_k<<<dim3(256, 2), 256, 0, stream>>>(query, key, bqm, bkm, bqs, bks, WT, P);
  scores_k<<<dim3(16, 16, 8), 256, 0, stream>>>(P, mask, (float*)d_out);
}

// Round 3
// 596.477 us; speedup vs baseline: 1.1124x; 1.1124x over previous
//
#include <hip/hip_runtime.h>

// GaussianActionDistGenerator: dual projection (mean/std) + masked tanh-clipped scores.
// B=8, L=2048, D=128. out = (s_mean [B,L,L], s_std [B,L,L]) f32, concatenated.

#define B_ 8
#define L_ 2048
#define D_ 128
#define NP (B_ * L_ * D_)            // 2,097,152 elems per projection array
#define BLL ((size_t)B_ * L_ * L_)   // 33,554,432 elems per output tensor

typedef __attribute__((ext_vector_type(8))) short short8;
typedef __attribute__((ext_vector_type(4))) float f32x4;

__device__ __forceinline__ unsigned short f32_bf16(float x) {
  unsigned u = __float_as_uint(x);
  u += 0x7FFF + ((u >> 16) & 1);   // round-to-nearest-even on the bf16 boundary
  return (unsigned short)(u >> 16);
}
__device__ __forceinline__ float bf16_f32(unsigned short h) {
  return __uint_as_float(((unsigned)h) << 16);
}
__device__ __forceinline__ float fast_tanh(float x) {
  // tanh(x) = 1 - 2/(exp(2x)+1); saturates correctly at +/-inf
  float e = __expf(2.0f * x);
  return 1.0f - 2.0f * __builtin_amdgcn_rcpf(e + 1.0f);
}

// ---------------------------------------------------------------------------
// Kernel 0: transpose weights [k][n] -> [n][k] and split f32 -> bf16 hi/lo.
// WT layout (ushort): WT[p*16384 + n*128 + k] (hi), WT[(4+p)*16384 + ...] (lo)
// ---------------------------------------------------------------------------
__global__ __launch_bounds__(256) void prep_w(
    const float* __restrict__ w0, const float* __restrict__ w1,
    const float* __restrict__ w2, const float* __restrict__ w3,
    unsigned short* __restrict__ WT) {
  int p = blockIdx.x;
  const float* W = (p == 0) ? w0 : (p == 1) ? w1 : (p == 2) ? w2 : w3;
  int idx = blockIdx.y * 256 + threadIdx.x;   // 0..16383 = k*128+n
  int k = idx >> 7, n = idx & 127;
  float v = W[idx];
  unsigned short h = f32_bf16(v);
  WT[p * 16384 + n * 128 + k] = h;
  WT[(4 + p) * 16384 + n * 128 + k] = f32_bf16(v - bf16_f32(h));
}

// ---------------------------------------------------------------------------
// Kernel 0b: split query/key f32 -> bf16 hi/lo planes, fully coalesced.
// XS layout (ushort): [query_hi NP][query_lo NP][key_hi NP][key_lo NP]
// ---------------------------------------------------------------------------
__global__ __launch_bounds__(256) void split_x(
    const float* __restrict__ q, const float* __restrict__ k,
    unsigned short* __restrict__ XS) {
  size_t idx = ((size_t)blockIdx.x * 256 + threadIdx.x) * 8;
  const float* src;
  unsigned short* dh;
  if (idx < (size_t)NP) {
    src = q + idx;
    dh = XS + idx;
  } else {
    src = k + (idx - NP);
    dh = XS + 2 * (size_t)NP + (idx - NP);
  }
  unsigned short* dl = dh + NP;
  f32x4 v0 = *(const f32x4*)src;
  f32x4 v1 = *(const f32x4*)(src + 4);
  short8 h, l;
#pragma unroll
  for (int j = 0; j < 4; j++) {
    unsigned short hh = f32_bf16(v0[j]);
    h[j] = (short)hh;
    l[j] = (short)f32_bf16(v0[j] - bf16_f32(hh));
    unsigned short hg = f32_bf16(v1[j]);
    h[4 + j] = (short)hg;
    l[4 + j] = (short)f32_bf16(v1[j] - bf16_f32(hg));
  }
  *(short8*)dh = h;
  *(short8*)dl = l;
}

// ---------------------------------------------------------------------------
// Kernel 1: projections. y=0: query -> qm (p0), qs (p2); y=1: key -> km (p1), ks (p3).
// Each block: 64 tokens, 4 waves x 16 tokens. MFMA 16x16x32 bf16, hi/lo 3-product split.
// A-fragments come from pre-split XS (16B/lane loads).
// Output P (ushort): P[p*NP + token*128 + d] hi, P[(4+p)*NP + ...] lo.
// ---------------------------------------------------------------------------
__global__ __launch_bounds__(256) void proj_k(
    const unsigned short* __restrict__ XS,
    const float* __restrict__ bqm, const float* __restrict__ bkm,
    const float* __restrict__ bqs, const float* __restrict__ bks,
    const unsigned short* __restrict__ WT,
    unsigned short* __restrict__ P) {
  const int y = blockIdx.y;
  const unsigned short* Xh = XS + (size_t)y * 2 * NP;
  const unsigned short* Xl = Xh + NP;
  const float* bias_m = y ? bkm : bqm;
  const float* bias_s = y ? bks : bqs;
  const int pm = y, ps = y + 2;
  const int wave = threadIdx.x >> 6, lane = threadIdx.x & 63;
  const int lr = lane & 15, kq = lane >> 4;
  const int rowbase = blockIdx.x * 64 + wave * 16;

  const unsigned short* wmh = WT + pm * 16384;
  const unsigned short* wml = WT + (4 + pm) * 16384;
  const unsigned short* wsh = WT + ps * 16384;
  const unsigned short* wsl = WT + (4 + ps) * 16384;

  f32x4 accm[8], accs[8];
#pragma unroll
  for (int i = 0; i < 8; i++) {
    accm[i] = f32x4{0.f, 0.f, 0.f, 0.f};
    accs[i] = f32x4{0.f, 0.f, 0.f, 0.f};
  }

#pragma unroll
  for (int ks = 0; ks < 4; ks++) {
    const int koff = ks * 32 + kq * 8;
    const int ao = (rowbase + lr) * D_ + koff;
    short8 a_hi = *(const short8*)(Xh + ao);
    short8 a_lo = *(const short8*)(Xl + ao);
#pragma unroll
    for (int nt = 0; nt < 8; nt++) {
      const int wo = (nt * 16 + lr) * 128 + koff;
      short8 bh = *(const short8*)(wmh + wo);
      short8 bl = *(const short8*)(wml + wo);
      accm[nt] = __builtin_amdgcn_mfma_f32_16x16x32_bf16(a_hi, bh, accm[nt], 0, 0, 0);
      accm[nt] = __builtin_amdgcn_mfma_f32_16x16x32_bf16(a_lo, bh, accm[nt], 0, 0, 0);
      accm[nt] = __builtin_amdgcn_mfma_f32_16x16x32_bf16(a_hi, bl, accm[nt], 0, 0, 0);
      short8 ch = *(const short8*)(wsh + wo);
      short8 cl = *(const short8*)(wsl + wo);
      accs[nt] = __builtin_amdgcn_mfma_f32_16x16x32_bf16(a_hi, ch, accs[nt], 0, 0, 0);
      accs[nt] = __builtin_amdgcn_mfma_f32_16x16x32_bf16(a_lo, ch, accs[nt], 0, 0, 0);
      accs[nt] = __builtin_amdgcn_mfma_f32_16x16x32_bf16(a_hi, cl, accs[nt], 0, 0, 0);
    }
  }

  unsigned short* Pmh = P + pm * NP;
  unsigned short* Pml = P + (4 + pm) * NP;
  unsigned short* Psh = P + ps * NP;
  unsigned short* Psl = P + (4 + ps) * NP;
#pragma unroll
  for (int nt = 0; nt < 8; nt++) {
    const int col = nt * 16 + lr;
    const float bm = bias_m[col];
    const float bs = bias_s[col];
#pragma unroll
    for (int r = 0; r < 4; r++) {
      const int token = rowbase + kq * 4 + r;
      const int o = token * D_ + col;
      float vm = accm[nt][r] + bm;
      unsigned short h = f32_bf16(vm);
      Pmh[o] = h;
      Pml[o] = f32_bf16(vm - bf16_f32(h));
      float vs = accs[nt][r] + bs;
      unsigned short g = f32_bf16(vs);
      Psh[o] = g;
      Psl[o] = f32_bf16(vs - bf16_f32(g));
    }
  }
}

// ---------------------------------------------------------------------------
// Kernel 2: masked scores. Per block: one batch, 128x128 output tile,
// 4 waves in 2x2, each wave 64x64. NT GEMM over D=128, hi/lo 3-product split,
// mean and std fused (one mask read). Epilogue: LDS transpose -> coalesced
// float4 stores, int4 mask loads, mask bits cached in a u64 for the std pass.
// ---------------------------------------------------------------------------
__global__ __launch_bounds__(256, 2) void scores_k(
    const unsigned short* __restrict__ P,
    const int* __restrict__ mask,
    float* __restrict__ out) {
  const int b = blockIdx.z;
  const int q0 = blockIdx.y * 128, c0 = blockIdx.x * 128;
  const int tid = threadIdx.x;
  const int wave = tid >> 6, lane = tid & 63;
  const int wr = wave >> 1, wc = wave & 1;
  const int lr = lane & 15, kq = lane >> 4;

  __shared__ float lt[128 * 128];   // 64 KB, reused for mean then std

  const int qrow = b * L_ + q0 + wr * 64;
  const int crow = b * L_ + c0 + wc * 64;
  const unsigned short* Qmh = P + 0 * (size_t)NP + (size_t)qrow * D_;
  const unsigned short* Qml = P + 4 * (size_t)NP + (size_t)qrow * D_;
  const unsigned short* Kmh = P + 1 * (size_t)NP + (size_t)crow * D_;
  const unsigned short* Kml = P + 5 * (size_t)NP + (size_t)crow * D_;
  const unsigned short* Qsh = P + 2 * (size_t)NP + (size_t)qrow * D_;
  const unsigned short* Qsl = P + 6 * (size_t)NP + (size_t)qrow * D_;
  const unsigned short* Ksh = P + 3 * (size_t)NP + (size_t)crow * D_;
  const unsigned short* Ksl = P + 7 * (size_t)NP + (size_t)crow * D_;

  f32x4 am[4][4], as_[4][4];
#pragma unroll
  for (int i = 0; i < 4; i++)
#pragma unroll
    for (int j = 0; j < 4; j++) {
      am[i][j] = f32x4{0.f, 0.f, 0.f, 0.f};
      as_[i][j] = f32x4{0.f, 0.f, 0.f, 0.f};
    }

#pragma unroll
  for (int ks = 0; ks < 4; ks++) {
    const int koff = ks * 32 + kq * 8;
    short8 qh[4], ql[4], kh[4], kl[4];
#pragma unroll
    for (int t = 0; t < 4; t++) {
      const int ro = (t * 16 + lr) * D_ + koff;
      qh[t] = *(const short8*)(Qmh + ro);
      ql[t] = *(const short8*)(Qml + ro);
      kh[t] = *(const short8*)(Kmh + ro);
      kl[t] = *(const short8*)(Kml + ro);
    }
#pragma unroll
    for (int mi = 0; mi < 4; mi++)
#pragma unroll
      for (int ni = 0; ni < 4; ni++) {
        am[mi][ni] = __builtin_amdgcn_mfma_f32_16x16x32_bf16(qh[mi], kh[ni], am[mi][ni], 0, 0, 0);
        am[mi][ni] = __builtin_amdgcn_mfma_f32_16x16x32_bf16(ql[mi], kh[ni], am[mi][ni], 0, 0, 0);
        am[mi][ni] = __builtin_amdgcn_mfma_f32_16x16x32_bf16(qh[mi], kl[ni], am[mi][ni], 0, 0, 0);
      }
#pragma unroll
    for (int t = 0; t < 4; t++) {
      const int ro = (t * 16 + lr) * D_ + koff;
      qh[t] = *(const short8*)(Qsh + ro);
      ql[t] = *(const short8*)(Qsl + ro);
      kh[t] = *(const short8*)(Ksh + ro);
      kl[t] = *(const short8*)(Ksl + ro);
    }
#pragma unroll
    for (int mi = 0; mi < 4; mi++)
#pragma unroll
      for (int ni = 0; ni < 4; ni++) {
        as_[mi][ni] = __builtin_amdgcn_mfma_f32_16x16x32_bf16(qh[mi], kh[ni], as_[mi][ni], 0, 0, 0);
        as_[mi][ni] = __builtin_amdgcn_mfma_f32_16x16x32_bf16(ql[mi], kh[ni], as_[mi][ni], 0, 0, 0);
        as_[mi][ni] = __builtin_amdgcn_mfma_f32_16x16x32_bf16(qh[mi], kl[ni], as_[mi][ni], 0, 0, 0);
      }
  }

  const float rs = 0.08838834764831845f;  // 1/sqrt(128)

  // ---- pass 1: mean ----
#pragma unroll
  for (int mi = 0; mi < 4; mi++)
#pragma unroll
    for (int r = 0; r < 4; r++) {
      const int row = wr * 64 + mi * 16 + kq * 4 + r;
      const int xr = ((row >> 2) & 3) << 4;   // bank swizzle: 4-way -> 2-way (free)
#pragma unroll
      for (int ni = 0; ni < 4; ni++) {
        const int col = wc * 64 + ni * 16 + lr;
        lt[row * 128 + (col ^ xr)] = am[mi][ni][r];
      }
    }
  __syncthreads();

  unsigned long long mbits = 0ull;
#pragma unroll
  for (int it = 0; it < 16; it++) {
    const int idx = it * 256 + tid;
    const int row = idx >> 5;
    const int c4 = (idx & 31) * 4;
    const int xr = ((row >> 2) & 3) << 4;
    f32x4 v = *(const f32x4*)&lt[row * 128 + (c4 ^ xr)];
    const size_t ob = ((size_t)(b * L_ + q0 + row)) * L_ + c0 + c4;
    int4 m4 = *(const int4*)&mask[ob];
    int mv[4] = {m4.x, m4.y, m4.z, m4.w};
    f32x4 o;
#pragma unroll
    for (int j = 0; j < 4; j++) {
      float tm = fast_tanh(v[j] * rs);
      o[j] = mv[j] ? (0.5f * tm + 0.5f) : 0.0f;
      if (mv[j]) mbits |= (1ull << (it * 4 + j));
    }
    *(f32x4*)&out[ob] = o;
  }
  __syncthreads();

  // ---- pass 2: std ----
#pragma unroll
  for (int mi = 0; mi < 4; mi++)
#pragma unroll
    for (int r = 0; r < 4; r++) {
      const int row = wr * 64 + mi * 16 + kq * 4 + r;
      const int xr = ((row >> 2) & 3) << 4;
#pragma unroll
      for (int ni = 0; ni < 4; ni++) {
        const int col = wc * 64 + ni * 16 + lr;
        lt[row * 128 + (col ^ xr)] = as_[mi][ni][r];
      }
    }
  __syncthreads();

#pragma unroll
  for (int it = 0; it < 16; it++) {
    const int idx = it * 256 + tid;
    const int row = idx >> 5;
    const int c4 = (idx & 31) * 4;
    const int xr = ((row >> 2) & 3) << 4;
    f32x4 v = *(const f32x4*)&lt[row * 128 + (c4 ^ xr)];
    const size_t ob = ((size_t)(b * L_ + q0 + row)) * L_ + c0 + c4;
    f32x4 o;
#pragma unroll
    for (int j = 0; j < 4; j++) {
      float ts = fast_tanh(v[j] * rs);
      const bool mv = (mbits >> (it * 4 + j)) & 1ull;
      o[j] = mv ? (4.0f * ts - 6.0f) : -10.0f;
    }
    *(f32x4*)&out[BLL + ob] = o;
  }
}

extern "C" void kernel_launch(void* const* d_in, const int* in_sizes, int n_in,
                              void* d_out, int out_size, void* d_ws, size_t ws_size,
                              hipStream_t stream) {
  const float* query = (const float*)d_in[0];
  const float* key   = (const float*)d_in[1];
  const int*   mask  = (const int*)d_in[2];
  const float* Wqm   = (const float*)d_in[3];
  const float* bqm   = (const float*)d_in[4];
  const float* Wkm   = (const float*)d_in[5];
  const float* bkm   = (const float*)d_in[6];
  const float* Wqs   = (const float*)d_in[7];
  const float* bqs   = (const float*)d_in[8];
  const float* Wks   = (const float*)d_in[9];
  const float* bks   = (const float*)d_in[10];

  unsigned short* P  = (unsigned short*)d_ws;       // 8 * NP ushorts = 33.55 MB
  unsigned short* WT = P + 8 * (size_t)NP;          // 8 * 16384 ushorts
  unsigned short* XS = WT + 8 * 16384;              // 4 * NP ushorts = 16.8 MB

  prep_w<<<dim3(4, 64), 256, 0, stream>>>(Wqm, Wkm, Wqs, Wks, WT);
  split_x<<<dim3(2048), 256, 0, stream>>>(query, key, XS);
  proj_k<<<dim3(256, 2), 256, 0, stream>>>(XS, bqm, bkm, bqs, bks, WT, P);
  scores_k<<<dim3(16, 16, 8), 256, 0, stream>>>(P, mask, (float*)d_out);
}